// Round 1
// baseline (671.187 us; speedup 1.0000x reference)
//
#include <hip/hip_runtime.h>

#define KDIM 32

// ---------------- CSR build ----------------

__global__ void hist_kernel(const int* __restrict__ centers, int* __restrict__ counts, int n) {
    int i = blockIdx.x * blockDim.x + threadIdx.x;
    if (i < n) atomicAdd(&counts[centers[i]], 1);
}

// single-block scan: 256 threads, each owns a contiguous chunk
__global__ void scan_kernel(const int* __restrict__ counts, int* __restrict__ offsets,
                            int* __restrict__ cursor, int n) {
    __shared__ int lds[256];
    int t = threadIdx.x;
    int chunk = (n + 255) >> 8;
    int s = t * chunk;
    int e = min(s + chunk, n);
    int sum = 0;
    for (int i = s; i < e; i++) sum += counts[i];
    lds[t] = sum;
    __syncthreads();
    for (int off = 1; off < 256; off <<= 1) {
        int v = (t >= off) ? lds[t - off] : 0;
        __syncthreads();
        lds[t] += v;
        __syncthreads();
    }
    int run = lds[t] - sum;  // exclusive prefix
    for (int i = s; i < e; i++) {
        int c = counts[i];
        offsets[i] = run;
        cursor[i] = run;
        run += c;
    }
    if (t == 255) offsets[n] = run;  // == E
}

__global__ void scatter_kernel(const int* __restrict__ centers, int* __restrict__ cursor,
                               int* __restrict__ edge_ids, int n) {
    int i = blockIdx.x * blockDim.x + threadIdx.x;
    if (i < n) {
        int c = centers[i];
        int pos = atomicAdd(&cursor[c], 1);
        edge_ids[pos] = i;
    }
}

// ---------------- main: one wave per atom ----------------
// lane = h*32 + k ; lane owns output rows mm = h + 2j (j=0..7), column k.
// l(mm): mm0->l0, mm1..3->l1, mm4..8->l2, mm9..15->l3
//  j=0: mm=h    -> t = h? t1 : t0
//  j=1: mm=2+h  -> t1
//  j=2: mm=4+h  -> t2
//  j=3: mm=6+h  -> t2
//  j=4: mm=8+h  -> t = h? t3 : t2
//  j=5..7       -> t3

__global__ __launch_bounds__(256) void imp_main_kernel(
    const float* __restrict__ sh, const float* __restrict__ rb,
    const float* __restrict__ emb, const int* __restrict__ neighbors,
    const int* __restrict__ offsets, const int* __restrict__ edge_ids,
    float* __restrict__ out, int n_atoms) {
    int wave = (blockIdx.x * blockDim.x + threadIdx.x) >> 6;
    int lane = threadIdx.x & 63;
    if (wave >= n_atoms) return;
    int k = lane & 31;
    int h = lane >> 5;
    bool hb = (h != 0);

    int start = offsets[wave];
    int end   = offsets[wave + 1];

    float a0 = 0.f, a1 = 0.f, a2 = 0.f, a3 = 0.f;
    float a4 = 0.f, a5 = 0.f, a6 = 0.f, a7 = 0.f;

    for (int i = start; i < end; i++) {
        int e = edge_ids[i];
        e = __builtin_amdgcn_readfirstlane(e);          // wave-uniform -> scalar path
        int nn = neighbors[e];
        nn = __builtin_amdgcn_readfirstlane(nn);

        float embv = emb[(size_t)nn * KDIM + k];        // 128B coalesced, L2-resident

        const float* rbp = rb + (size_t)e * (4 * KDIM);
        float t0 = rbp[0 * KDIM + k] * embv;
        float t1 = rbp[1 * KDIM + k] * embv;
        float t2 = rbp[2 * KDIM + k] * embv;
        float t3 = rbp[3 * KDIM + k] * embv;

        const float4* shp = (const float4*)(sh + (size_t)e * 16);
        float4 s0 = shp[0];
        float4 s1 = shp[1];
        float4 s2 = shp[2];
        float4 s3 = shp[3];

        float ta = hb ? t1 : t0;   // j=0
        float td = hb ? t3 : t2;   // j=4

        a0 += (hb ? s0.y : s0.x) * ta;
        a1 += (hb ? s0.w : s0.z) * t1;
        a2 += (hb ? s1.y : s1.x) * t2;
        a3 += (hb ? s1.w : s1.z) * t2;
        a4 += (hb ? s2.y : s2.x) * td;
        a5 += (hb ? s2.w : s2.z) * t3;
        a6 += (hb ? s3.y : s3.x) * t3;
        a7 += (hb ? s3.w : s3.z) * t3;
    }

    const float SCALE = 0.1f;
    float* op = out + (size_t)wave * (16 * KDIM) + k;
    op[(h + 0)  * KDIM] = a0 * SCALE;
    op[(h + 2)  * KDIM] = a1 * SCALE;
    op[(h + 4)  * KDIM] = a2 * SCALE;
    op[(h + 6)  * KDIM] = a3 * SCALE;
    op[(h + 8)  * KDIM] = a4 * SCALE;
    op[(h + 10) * KDIM] = a5 * SCALE;
    op[(h + 12) * KDIM] = a6 * SCALE;
    op[(h + 14) * KDIM] = a7 * SCALE;
}

extern "C" void kernel_launch(void* const* d_in, const int* in_sizes, int n_in,
                              void* d_out, int out_size, void* d_ws, size_t ws_size,
                              hipStream_t stream) {
    const float* sh        = (const float*)d_in[0];   // (E, 16)
    const float* rb        = (const float*)d_in[1];   // (E, 4, 32)
    const float* emb       = (const float*)d_in[2];   // (N, 32)
    const int*   centers   = (const int*)d_in[3];     // (E,)
    const int*   neighbors = (const int*)d_in[4];     // (E,)

    int E = in_sizes[3];
    int N = in_sizes[2] / KDIM;

    float* out = (float*)d_out;

    int* counts   = (int*)d_ws;          // N
    int* offsets  = counts + N;          // N+1
    int* cursor   = offsets + N + 1;     // N
    int* edge_ids = cursor + N;          // E

    hipMemsetAsync(counts, 0, (size_t)N * sizeof(int), stream);

    hist_kernel<<<(E + 255) / 256, 256, 0, stream>>>(centers, counts, E);
    scan_kernel<<<1, 256, 0, stream>>>(counts, offsets, cursor, N);
    scatter_kernel<<<(E + 255) / 256, 256, 0, stream>>>(centers, cursor, edge_ids, E);

    int waves = N;                        // one wave per atom
    int blocks = (waves * 64 + 255) / 256;
    imp_main_kernel<<<blocks, 256, 0, stream>>>(sh, rb, emb, neighbors, offsets,
                                                edge_ids, out, N);
}

// Round 2
// 606.206 us; speedup vs baseline: 1.1072x; 1.1072x over previous
//
#include <hip/hip_runtime.h>

#define KDIM 32

// ---------------- CSR build ----------------

__global__ void hist_kernel(const int* __restrict__ centers, int* __restrict__ counts, int n) {
    int i = blockIdx.x * blockDim.x + threadIdx.x;
    if (i < n) atomicAdd(&counts[centers[i]], 1);
}

// single-block scan: 1024 threads, each owns a contiguous chunk
__global__ __launch_bounds__(1024) void scan_kernel(const int* __restrict__ counts,
                                                    int* __restrict__ offsets,
                                                    int* __restrict__ cursor, int n) {
    __shared__ int lds[1024];
    int t = threadIdx.x;
    int chunk = (n + 1023) >> 10;
    int s = t * chunk;
    int e = min(s + chunk, n);
    int sum = 0;
    for (int i = s; i < e; i++) sum += counts[i];
    lds[t] = sum;
    __syncthreads();
    for (int off = 1; off < 1024; off <<= 1) {
        int v = (t >= off) ? lds[t - off] : 0;
        __syncthreads();
        lds[t] += v;
        __syncthreads();
    }
    int run = lds[t] - sum;  // exclusive prefix
    for (int i = s; i < e; i++) {
        int c = counts[i];
        offsets[i] = run;
        cursor[i] = run;
        run += c;
    }
    if (t == 1023) offsets[n] = run;  // == E
}

// writes (edge_id, neighbor_id) records so the main loop avoids the
// dependent neighbors[e] load
__global__ void scatter_kernel(const int* __restrict__ centers,
                               const int* __restrict__ neighbors,
                               int* __restrict__ cursor,
                               int2* __restrict__ recs, int n) {
    int i = blockIdx.x * blockDim.x + threadIdx.x;
    if (i < n) {
        int c = centers[i];
        int nn = neighbors[i];
        int pos = atomicAdd(&cursor[c], 1);
        recs[pos] = make_int2(i, nn);
    }
}

// ---------------- main: one wave per atom ----------------
// lane = h*32 + k ; lane owns output rows mm = 8h + j (j=0..7), column k.
// l(mm): mm0->l0, mm1..3->l1, mm4..8->l2, mm9..15->l3
//  h=0: j=0 -> t0 ; j=1..3 -> t1 ; j=4..7 -> t2
//  h=1: j=0 -> t2 ; j=1..7 -> t3
// sh needed by lane: sh[e*16 + 8h + j], j=0..7 -> two float4 loads, no selects.

#define EDGE_BODY(EB, RP, SHP)                                            \
    {                                                                     \
        float t0 = RP[0 * KDIM + k] * EB;                                 \
        float t1 = RP[1 * KDIM + k] * EB;                                 \
        float t2 = RP[2 * KDIM + k] * EB;                                 \
        float t3 = RP[3 * KDIM + k] * EB;                                 \
        float4 sA = SHP[0];                                               \
        float4 sB = SHP[1];                                               \
        float c0 = hb ? t2 : t0;                                          \
        float c1 = hb ? t3 : t1;                                          \
        float c2 = hb ? t3 : t2;                                          \
        a0 += sA.x * c0;                                                  \
        a1 += sA.y * c1;                                                  \
        a2 += sA.z * c1;                                                  \
        a3 += sA.w * c1;                                                  \
        a4 += sB.x * c2;                                                  \
        a5 += sB.y * c2;                                                  \
        a6 += sB.z * c2;                                                  \
        a7 += sB.w * c2;                                                  \
    }

__global__ __launch_bounds__(256) void imp_main_kernel(
    const float* __restrict__ sh, const float* __restrict__ rb,
    const float* __restrict__ emb, const int2* __restrict__ recs,
    const int* __restrict__ offsets, float* __restrict__ out, int n_atoms) {
    int wave = (blockIdx.x * blockDim.x + threadIdx.x) >> 6;
    int lane = threadIdx.x & 63;
    if (wave >= n_atoms) return;
    int k = lane & 31;
    int h = lane >> 5;
    bool hb = (h != 0);

    int start = offsets[wave];
    int end   = offsets[wave + 1];

    float a0 = 0.f, a1 = 0.f, a2 = 0.f, a3 = 0.f;
    float a4 = 0.f, a5 = 0.f, a6 = 0.f, a7 = 0.f;

    int i = start;
    for (; i + 4 <= end; i += 4) {
        int2 r0 = recs[i + 0];
        int2 r1 = recs[i + 1];
        int2 r2 = recs[i + 2];
        int2 r3 = recs[i + 3];
        int e0 = __builtin_amdgcn_readfirstlane(r0.x);
        int n0 = __builtin_amdgcn_readfirstlane(r0.y);
        int e1 = __builtin_amdgcn_readfirstlane(r1.x);
        int n1 = __builtin_amdgcn_readfirstlane(r1.y);
        int e2 = __builtin_amdgcn_readfirstlane(r2.x);
        int n2 = __builtin_amdgcn_readfirstlane(r2.y);
        int e3 = __builtin_amdgcn_readfirstlane(r3.x);
        int n3 = __builtin_amdgcn_readfirstlane(r3.y);

        float eb0 = emb[(size_t)n0 * KDIM + k];
        float eb1 = emb[(size_t)n1 * KDIM + k];
        float eb2 = emb[(size_t)n2 * KDIM + k];
        float eb3 = emb[(size_t)n3 * KDIM + k];

        const float* rp0 = rb + (size_t)e0 * (4 * KDIM);
        const float* rp1 = rb + (size_t)e1 * (4 * KDIM);
        const float* rp2 = rb + (size_t)e2 * (4 * KDIM);
        const float* rp3 = rb + (size_t)e3 * (4 * KDIM);

        const float4* sp0 = (const float4*)(sh + (size_t)e0 * 16 + 8 * h);
        const float4* sp1 = (const float4*)(sh + (size_t)e1 * 16 + 8 * h);
        const float4* sp2 = (const float4*)(sh + (size_t)e2 * 16 + 8 * h);
        const float4* sp3 = (const float4*)(sh + (size_t)e3 * 16 + 8 * h);

        EDGE_BODY(eb0, rp0, sp0)
        EDGE_BODY(eb1, rp1, sp1)
        EDGE_BODY(eb2, rp2, sp2)
        EDGE_BODY(eb3, rp3, sp3)
    }
    for (; i < end; i++) {
        int2 r0 = recs[i];
        int e0 = __builtin_amdgcn_readfirstlane(r0.x);
        int n0 = __builtin_amdgcn_readfirstlane(r0.y);
        float eb0 = emb[(size_t)n0 * KDIM + k];
        const float* rp0 = rb + (size_t)e0 * (4 * KDIM);
        const float4* sp0 = (const float4*)(sh + (size_t)e0 * 16 + 8 * h);
        EDGE_BODY(eb0, rp0, sp0)
    }

    const float SCALE = 0.1f;
    float* op = out + (size_t)wave * (16 * KDIM) + (size_t)(8 * h) * KDIM + k;
    op[0 * KDIM] = a0 * SCALE;
    op[1 * KDIM] = a1 * SCALE;
    op[2 * KDIM] = a2 * SCALE;
    op[3 * KDIM] = a3 * SCALE;
    op[4 * KDIM] = a4 * SCALE;
    op[5 * KDIM] = a5 * SCALE;
    op[6 * KDIM] = a6 * SCALE;
    op[7 * KDIM] = a7 * SCALE;
}

extern "C" void kernel_launch(void* const* d_in, const int* in_sizes, int n_in,
                              void* d_out, int out_size, void* d_ws, size_t ws_size,
                              hipStream_t stream) {
    const float* sh        = (const float*)d_in[0];   // (E, 16)
    const float* rb        = (const float*)d_in[1];   // (E, 4, 32)
    const float* emb       = (const float*)d_in[2];   // (N, 32)
    const int*   centers   = (const int*)d_in[3];     // (E,)
    const int*   neighbors = (const int*)d_in[4];     // (E,)

    int E = in_sizes[3];
    int N = in_sizes[2] / KDIM;

    float* out = (float*)d_out;

    int2* recs    = (int2*)d_ws;              // E records, 8B aligned at ws base
    int*  counts  = (int*)(recs + E);         // N
    int*  offsets = counts + N;               // N+1
    int*  cursor  = offsets + N + 1;          // N

    hipMemsetAsync(counts, 0, (size_t)N * sizeof(int), stream);

    hist_kernel<<<(E + 255) / 256, 256, 0, stream>>>(centers, counts, E);
    scan_kernel<<<1, 1024, 0, stream>>>(counts, offsets, cursor, N);
    scatter_kernel<<<(E + 255) / 256, 256, 0, stream>>>(centers, neighbors, cursor, recs, E);

    int blocks = (N * 64 + 255) / 256;        // one wave per atom
    imp_main_kernel<<<blocks, 256, 0, stream>>>(sh, rb, emb, recs, offsets, out, N);
}